// Round 12
// baseline (199.632 us; speedup 1.0000x reference)
//
#include <hip/hip_runtime.h>

static constexpr int B = 4, S = 1024, D = 512;

typedef __attribute__((ext_vector_type(8))) short short8;
typedef __attribute__((ext_vector_type(4))) float f32x4;

// Static device scratch.
__device__ float g_alpha[B * S];
__device__ float g_beta[B * S];
__device__ float g_nup[B * S];
__device__ float g_C[B * S];
__device__ float g_prsd[B * S];        // prior superdiagonal gather
__device__ float g_tupart[16][B * S];
__device__ float g_tdpart[16][B * S];
__device__ float g_vq[D];
__device__ float g_vk[D];
__device__ float g_c0[1];
__device__ unsigned g_cnt;             // last-block ticket (zeroed in k1 each call)

__device__ __forceinline__ float wred(float v) {
#pragma unroll
  for (int o = 32; o; o >>= 1) v += __shfl_down(v, o, 64);
  return v;
}
__device__ __forceinline__ float wredx(float v) {  // all lanes get total
#pragma unroll
  for (int o = 32; o; o >>= 1) v += __shfl_xor(v, o, 64);
  return v;
}

__device__ __forceinline__ ushort f2bf(float f) {
  union { float f; unsigned u; } x;
  x.f = f;
  unsigned r = x.u + 0x7fffu + ((x.u >> 16) & 1u);  // RNE
  return (ushort)(r >> 16);
}
__device__ __forceinline__ float bf2f(ushort u) {
  union { unsigned u; float f; } x;
  x.u = ((unsigned)u) << 16;
  return x.f;
}

// ========== k1: LN (wave/row) || M-GEMM || bias folds || prior gather ======
// blocks [0,1024): LN rows bid*4+w
// blocks [1024,1088): Mt = Wk@Wq^T 64x64 tile
// blocks [1088,1216): vq/vk rows (+c0 on first)
// blocks [1216,1224): prior superdiag gather (+g_cnt reset)
__global__ __launch_bounds__(256) void k1(
    const float* __restrict__ ctx, const float* __restrict__ gamma,
    const float* __restrict__ beta, const float* __restrict__ Wq,
    const float* __restrict__ bq, const float* __restrict__ Wk,
    const float* __restrict__ bk, const float* __restrict__ prior,
    unsigned* __restrict__ Xb, ushort* __restrict__ Mt) {
  __shared__ __align__(16) char smem[16384];
  const int bid = blockIdx.x, tid = threadIdx.x;
  const int w = tid >> 6, l = tid & 63;

  if (bid < 1024) {  // ---- LayerNorm, wave-per-row, no barriers ----
    const int row = bid * 4 + w;
    const float4* src = reinterpret_cast<const float4*>(ctx + (size_t)row * D);
    const float4 a0 = src[l * 2], a1 = src[l * 2 + 1];
    float sum = a0.x + a0.y + a0.z + a0.w + a1.x + a1.y + a1.z + a1.w;
    sum = wredx(sum);
    const float mu = sum * (1.0f / (float)D);
    float d[8] = {a0.x - mu, a0.y - mu, a0.z - mu, a0.w - mu,
                  a1.x - mu, a1.y - mu, a1.z - mu, a1.w - mu};
    float s2 = 0.f;
#pragma unroll
    for (int i = 0; i < 8; ++i) s2 += d[i] * d[i];
    s2 = wredx(s2);
    const float var = s2 * (1.0f / (float)(D - 1));
    const float inv = 1.0f / (sqrtf(var) + 1e-6f);
    const float4 g0 = reinterpret_cast<const float4*>(gamma)[l * 2];
    const float4 g1 = reinterpret_cast<const float4*>(gamma)[l * 2 + 1];
    const float4 b0 = reinterpret_cast<const float4*>(beta)[l * 2];
    const float4 b1 = reinterpret_cast<const float4*>(beta)[l * 2 + 1];
    const float gg[8] = {g0.x, g0.y, g0.z, g0.w, g1.x, g1.y, g1.z, g1.w};
    const float bb[8] = {b0.x, b0.y, b0.z, b0.w, b1.x, b1.y, b1.z, b1.w};
    unsigned u[4];
#pragma unroll
    for (int j = 0; j < 4; ++j) {
      const float ox = gg[2 * j] * d[2 * j] * inv + bb[2 * j];
      const float oy = gg[2 * j + 1] * d[2 * j + 1] * inv + bb[2 * j + 1];
      u[j] = (unsigned)f2bf(ox) | ((unsigned)f2bf(oy) << 16);
    }
    reinterpret_cast<uint4*>(Xb + (size_t)row * (D / 2))[l] =
        make_uint4(u[0], u[1], u[2], u[3]);
  } else if (bid < 1088) {  // ---- M-GEMM tile ----
    short* As = (short*)smem;
    short* Bs = (short*)(smem + 8192);
    const int tI = bid - 1024;
    const int bi = (tI >> 3) * 64, bj = (tI & 7) * 64;
    const int wr = (w >> 1) * 32, wc = (w & 1) * 32;
    const int lrow = l & 15, lgrp = l >> 4;
    const int srow = tid >> 2, schunk = (tid & 3) * 2;
    f32x4 acc[2][2] = {};
    for (int kk = 0; kk < D; kk += 64) {
      short8 va0, va1, vb0, vb1;
      const float* sa = Wk + (size_t)(bi + srow) * D + kk + schunk * 8;
      const float* sb = Wq + (size_t)(bj + srow) * D + kk + schunk * 8;
#pragma unroll
      for (int i = 0; i < 2; ++i) {
        const float4 a0 = reinterpret_cast<const float4*>(sa)[2 * i];
        const float4 a1 = reinterpret_cast<const float4*>(sa)[2 * i + 1];
        const float4 b0 = reinterpret_cast<const float4*>(sb)[2 * i];
        const float4 b1 = reinterpret_cast<const float4*>(sb)[2 * i + 1];
        short8* pa = i ? &va1 : &va0;
        short8* pb = i ? &vb1 : &vb0;
        (*pa)[0] = (short)f2bf(a0.x); (*pa)[1] = (short)f2bf(a0.y);
        (*pa)[2] = (short)f2bf(a0.z); (*pa)[3] = (short)f2bf(a0.w);
        (*pa)[4] = (short)f2bf(a1.x); (*pa)[5] = (short)f2bf(a1.y);
        (*pa)[6] = (short)f2bf(a1.z); (*pa)[7] = (short)f2bf(a1.w);
        (*pb)[0] = (short)f2bf(b0.x); (*pb)[1] = (short)f2bf(b0.y);
        (*pb)[2] = (short)f2bf(b0.z); (*pb)[3] = (short)f2bf(b0.w);
        (*pb)[4] = (short)f2bf(b1.x); (*pb)[5] = (short)f2bf(b1.y);
        (*pb)[6] = (short)f2bf(b1.z); (*pb)[7] = (short)f2bf(b1.w);
      }
      const int sw = srow & 7;
      *reinterpret_cast<short8*>(&As[srow * 64 + ((schunk ^ sw) << 3)]) = va0;
      *reinterpret_cast<short8*>(&As[srow * 64 + (((schunk + 1) ^ sw) << 3)]) = va1;
      *reinterpret_cast<short8*>(&Bs[srow * 64 + ((schunk ^ sw) << 3)]) = vb0;
      *reinterpret_cast<short8*>(&Bs[srow * 64 + (((schunk + 1) ^ sw) << 3)]) = vb1;
      __syncthreads();
#pragma unroll
      for (int ks = 0; ks < 2; ++ks) {
        short8 af[2], bfr[2];
#pragma unroll
        for (int mi = 0; mi < 2; ++mi) {
          const int r = wr + 16 * mi + lrow;
          af[mi] = *reinterpret_cast<const short8*>(
              &As[r * 64 + (((ks * 4 + lgrp) ^ (r & 7)) << 3)]);
        }
#pragma unroll
        for (int ni = 0; ni < 2; ++ni) {
          const int r = wc + 16 * ni + lrow;
          bfr[ni] = *reinterpret_cast<const short8*>(
              &Bs[r * 64 + (((ks * 4 + lgrp) ^ (r & 7)) << 3)]);
        }
#pragma unroll
        for (int mi = 0; mi < 2; ++mi)
#pragma unroll
          for (int ni = 0; ni < 2; ++ni)
            acc[mi][ni] = __builtin_amdgcn_mfma_f32_16x16x32_bf16(
                af[mi], bfr[ni], acc[mi][ni], 0, 0, 0);
      }
      __syncthreads();
    }
#pragma unroll
    for (int mi = 0; mi < 2; ++mi)
#pragma unroll
      for (int ni = 0; ni < 2; ++ni)
#pragma unroll
        for (int v = 0; v < 4; ++v) {
          const int r = bi + wr + 16 * mi + (l >> 4) * 4 + v;
          const int c = bj + wc + 16 * ni + (l & 15);
          Mt[(size_t)r * D + c] = f2bf(acc[mi][ni][v]);
        }
  } else if (bid < 1216) {  // ---- bias folds ----
    const int i = (bid - 1088) * 4 + w;
    float sq = 0.f, sk = 0.f;
    for (int j = l; j < D; j += 64) {
      sq += Wq[(size_t)i * D + j] * bk[j];
      sk += Wk[(size_t)i * D + j] * bq[j];
    }
    sq = wred(sq);
    sk = wred(sk);
    if (l == 0) {
      g_vq[i] = sq;
      g_vk[i] = sk;
    }
    if (bid == 1088 && tid < 64) {
      float c = 0.f;
      for (int j = l; j < D; j += 64) c += bq[j] * bk[j];
      c = wred(c);
      if (l == 0) g_c0[0] = c;
    }
  } else {  // ---- prior superdiagonal gather + ticket reset ----
    if (bid == 1216 && tid == 0) g_cnt = 0u;
    const int g0 = ((bid - 1216) * 256 + tid) * 2;
#pragma unroll
    for (int r = 0; r < 2; ++r) {
      const int idx = g0 + r;
      const int b = idx >> 10, s = idx & (S - 1);
      g_prsd[idx] =
          (s < S - 1) ? prior[((size_t)b * S + s) * S + s + 1] : 0.0f;
    }
  }
}

// ========== k2: banddot (+alpha/beta) + last-block fused softmax/scan ======
__global__ __launch_bounds__(256) void k_banddot(const ushort* __restrict__ Xb2,
                                                 const ushort* __restrict__ Mt,
                                                 const int* __restrict__ eos) {
  __shared__ __align__(16) short As[64 * 64];
  __shared__ __align__(16) short Bs[64 * 64];
  __shared__ unsigned sticket;
  const int tid = threadIdx.x;
  const int r0 = (blockIdx.x & 63) * 64, n0 = (blockIdx.x >> 6) * 64;
  const int w = tid >> 6, l = tid & 63;
  const int wr = (w >> 1) * 32, wc = (w & 1) * 32;
  const int lrow = l & 15, lgrp = l >> 4;
  const int srow = tid >> 2, schunk = (tid & 3) * 2;
  const bool do_ab = (n0 == 0);
  f32x4 acc[2][2] = {};
  float a_p = 0.f, b_p = 0.f;
  for (int kk = 0; kk < D; kk += 64) {
    const short* sa = (const short*)Xb2 + (size_t)(r0 + srow) * D + kk + schunk * 8;
    const short* sb = (const short*)Mt + (size_t)(n0 + srow) * D + kk + schunk * 8;
    short8 va0 = reinterpret_cast<const short8*>(sa)[0];
    short8 va1 = reinterpret_cast<const short8*>(sa)[1];
    short8 vb0 = reinterpret_cast<const short8*>(sb)[0];
    short8 vb1 = reinterpret_cast<const short8*>(sb)[1];
    if (do_ab) {
      const int k0 = kk + schunk * 8;
#pragma unroll
      for (int j = 0; j < 8; ++j) {
        a_p += bf2f((ushort)va0[j]) * g_vq[k0 + j] +
               bf2f((ushort)va1[j]) * g_vq[k0 + 8 + j];
        b_p += bf2f((ushort)va0[j]) * g_vk[k0 + j] +
               bf2f((ushort)va1[j]) * g_vk[k0 + 8 + j];
      }
    }
    const int sw = srow & 7;
    *reinterpret_cast<short8*>(&As[srow * 64 + ((schunk ^ sw) << 3)]) = va0;
    *reinterpret_cast<short8*>(&As[srow * 64 + (((schunk + 1) ^ sw) << 3)]) = va1;
    *reinterpret_cast<short8*>(&Bs[srow * 64 + ((schunk ^ sw) << 3)]) = vb0;
    *reinterpret_cast<short8*>(&Bs[srow * 64 + (((schunk + 1) ^ sw) << 3)]) = vb1;
    __syncthreads();
#pragma unroll
    for (int ks = 0; ks < 2; ++ks) {
      short8 af[2], bfr[2];
#pragma unroll
      for (int mi = 0; mi < 2; ++mi) {
        const int r = wr + 16 * mi + lrow;
        af[mi] = *reinterpret_cast<const short8*>(
            &As[r * 64 + (((ks * 4 + lgrp) ^ (r & 7)) << 3)]);
      }
#pragma unroll
      for (int ni = 0; ni < 2; ++ni) {
        const int r = wc + 16 * ni + lrow;
        bfr[ni] = *reinterpret_cast<const short8*>(
            &Bs[r * 64 + (((ks * 4 + lgrp) ^ (r & 7)) << 3)]);
      }
#pragma unroll
      for (int mi = 0; mi < 2; ++mi)
#pragma unroll
        for (int ni = 0; ni < 2; ++ni)
          acc[mi][ni] = __builtin_amdgcn_mfma_f32_16x16x32_bf16(
              af[mi], bfr[ni], acc[mi][ni], 0, 0, 0);
    }
    __syncthreads();
  }
  if (do_ab) {
    a_p += __shfl_xor(a_p, 1, 64);
    a_p += __shfl_xor(a_p, 2, 64);
    b_p += __shfl_xor(b_p, 1, 64);
    b_p += __shfl_xor(b_p, 2, 64);
    if ((tid & 3) == 0) {
      g_alpha[r0 + srow] = a_p;
      g_beta[r0 + srow] = b_p;
    }
  }
  float tu[2][4] = {}, td[2][4] = {};
#pragma unroll
  for (int mi = 0; mi < 2; ++mi)
#pragma unroll
    for (int v = 0; v < 4; ++v) {
      const int grow = r0 + wr + 16 * mi + lgrp * 4 + v;
      const int sl = grow & (S - 1);
#pragma unroll
      for (int ni = 0; ni < 2; ++ni) {
        const int ncol = n0 + wc + 16 * ni + lrow;
        const float y = acc[mi][ni][v];
        if (sl < S - 1) tu[mi][v] += y * bf2f(Xb2[(size_t)(grow + 1) * D + ncol]);
        if (sl > 0) td[mi][v] += y * bf2f(Xb2[(size_t)(grow - 1) * D + ncol]);
      }
    }
#pragma unroll
  for (int m = 1; m <= 8; m <<= 1)
#pragma unroll
    for (int mi = 0; mi < 2; ++mi)
#pragma unroll
      for (int v = 0; v < 4; ++v) {
        tu[mi][v] += __shfl_xor(tu[mi][v], m, 64);
        td[mi][v] += __shfl_xor(td[mi][v], m, 64);
      }
  if (lrow == 0) {
    const int slot = (blockIdx.x >> 6) * 2 + (w & 1);
#pragma unroll
    for (int mi = 0; mi < 2; ++mi)
#pragma unroll
      for (int v = 0; v < 4; ++v) {
        const int grow = r0 + wr + 16 * mi + lgrp * 4 + v;
        g_tupart[slot][grow] = tu[mi][v];
        g_tdpart[slot][grow] = td[mi][v];
      }
  }
  // ---- last-block fused softmax + band value + scan (round-7 P3 body) ----
  __threadfence();
  __syncthreads();
  if (tid == 0) sticket = atomicAdd(&g_cnt, 1u);
  __syncthreads();
  if (sticket == 511u) {
    __threadfence();
    float* spp = (float*)As;  // 4KB
    float* swv = (float*)Bs;  // 4 floats
    const float c = g_c0[0];
    for (int b = 0; b < B; ++b) {
      float pnv[4], ppv[4];
#pragma unroll
      for (int r = 0; r < 4; ++r) {
        const int s = tid * 4 + r;
        const int idx = b * S + s;
        float tuv = 0.f, tdv = 0.f;
#pragma unroll
        for (int p = 0; p < 16; ++p) {
          tuv += g_tupart[p][idx];
          tdv += g_tdpart[p][idx];
        }
        const bool uvb = (s + 1 < S) && (eos[b * S + s + 1] != 0);
        const bool dvb = (s >= 1) && (eos[b * S + s - 1] != 0);
        const float su =
            uvb ? (tuv + g_alpha[idx] + g_beta[idx + 1] + c) * (1.0f / 256.0f)
                : -1e9f;
        const float sd =
            dvb ? (tdv + g_alpha[idx] + g_beta[idx - 1] + c) * (1.0f / 256.0f)
                : -1e9f;
        const float m = fmaxf(su, sd);
        const float eu = expf(su - m), ed = expf(sd - m);
        const float inv = 1.0f / (eu + ed);
        pnv[r] = eu * inv;
        ppv[r] = ed * inv;
        spp[s] = ppv[r];
      }
      __syncthreads();
      float Lv[4];
#pragma unroll
      for (int r = 0; r < 4; ++r) {
        const int s = tid * 4 + r;
        const int idx = b * S + s;
        float v = 0.f, L = 0.f;
        if (s < S - 1) {
          v = sqrtf(pnv[r] * spp[s + 1] + 1e-9f);
          const float pr = g_prsd[idx];
          L = logf(pr + (1.0f - pr) * v + 1e-9f);
        }
        g_nup[idx] = v;
        Lv[r] = L;
      }
      const float t0 = Lv[0], t1 = t0 + Lv[1], t2 = t1 + Lv[2], t3 = t2 + Lv[3];
      float incl = t3;
#pragma unroll
      for (int o = 1; o <= 32; o <<= 1) {
        const float u = __shfl_up(incl, o, 64);
        if (l >= o) incl += u;
      }
      if (l == 63) swv[w] = incl;
      __syncthreads();
      float base = incl - t3;
      for (int wv = 0; wv < w; ++wv) base += swv[wv];
      const int s0 = b * S + tid * 4;
      g_C[s0] = base;
      g_C[s0 + 1] = base + t0;
      g_C[s0 + 2] = base + t1;
      g_C[s0 + 3] = base + t2;
      __syncthreads();  // spp/swv reuse next batch
    }
  }
}

// ========== k4: final outputs ==========
__global__ __launch_bounds__(256) void k_final(const float* __restrict__ prior,
                                               float* __restrict__ out0,
                                               float* __restrict__ out1) {
  const int b = blockIdx.y, i = blockIdx.x, t = threadIdx.x;
  const size_t rowoff = ((size_t)b * S + i) * S;
  const float4 pr4 = reinterpret_cast<const float4*>(prior + rowoff)[t];
  const float4 cj4 = reinterpret_cast<const float4*>(g_C + b * S)[t];
  const float ci = g_C[b * S + i];
  const float SQ = sqrtf(1e-9f);
  const float prr[4] = {pr4.x, pr4.y, pr4.z, pr4.w};
  const float cjj[4] = {cj4.x, cj4.y, cj4.z, cj4.w};
  float o0[4], o1[4];
#pragma unroll
  for (int q = 0; q < 4; ++q) {
    const int j = t * 4 + q;
    const float p = prr[q];
    float v;
    if (j == i + 1) v = g_nup[b * S + i];
    else if (j == i - 1) v = g_nup[b * S + j];
    else v = SQ;
    o1[q] = p + (1.0f - p) * v;
    if (j == i) {
      o0[q] = p + (1.0f - p) * SQ;
    } else {
      const float d = (j > i) ? (cjj[q] - ci) : (ci - cjj[q]);
      o0[q] = expf(d) + 1e-9f;
    }
  }
  reinterpret_cast<float4*>(out0 + rowoff)[t] =
      make_float4(o0[0], o0[1], o0[2], o0[3]);
  reinterpret_cast<float4*>(out1 + rowoff)[t] =
      make_float4(o1[0], o1[1], o1[2], o1[3]);
}

extern "C" void kernel_launch(void* const* d_in, const int* in_sizes, int n_in,
                              void* d_out, int out_size, void* d_ws,
                              size_t ws_size, hipStream_t stream) {
  (void)in_sizes; (void)n_in; (void)out_size; (void)d_ws; (void)ws_size;
  const float* ctx = (const float*)d_in[0];
  const float* prior = (const float*)d_in[1];
  const float* Wq = (const float*)d_in[2];
  const float* bq = (const float*)d_in[3];
  const float* Wk = (const float*)d_in[4];
  const float* bk = (const float*)d_in[5];
  const float* gamma = (const float*)d_in[6];
  const float* beta = (const float*)d_in[7];
  const int* eos = (const int*)d_in[8];

  float* ob = (float*)d_out;
  float* out0 = ob;                      // [B,S,S]
  float* out1 = ob + (size_t)B * S * S;  // [B,S,S]
  unsigned* Xb = (unsigned*)ob;          // bf16 X (floats [0,1M))
  ushort* Mt = (ushort*)(ob + 1048576);  // bf16 Mt (floats [1M,1.125M))

  k1<<<1224, 256, 0, stream>>>(ctx, gamma, beta, Wq, bq, Wk, bk, prior, Xb, Mt);
  k_banddot<<<512, 256, 0, stream>>>((const ushort*)Xb, Mt, eos);
  k_final<<<dim3(S, B), 256, 0, stream>>>(prior, out0, out1);
}

// Round 13
// 125.994 us; speedup vs baseline: 1.5845x; 1.5845x over previous
//
#include <hip/hip_runtime.h>

static constexpr int B = 4, S = 1024, D = 512;

typedef __attribute__((ext_vector_type(8))) short short8;
typedef __attribute__((ext_vector_type(4))) float f32x4;

// Static device scratch.
__device__ float g_alpha[B * S];
__device__ float g_beta[B * S];
__device__ float g_nup[B * S];
__device__ float g_C[B * S];
__device__ float g_prsd[B * S];        // prior superdiagonal gather
__device__ float g_tupart[16][B * S];
__device__ float g_tdpart[16][B * S];
__device__ float g_vq[D];
__device__ float g_vk[D];
__device__ float g_c0[1];

__device__ __forceinline__ float wred(float v) {
#pragma unroll
  for (int o = 32; o; o >>= 1) v += __shfl_down(v, o, 64);
  return v;
}
__device__ __forceinline__ float wredx(float v) {  // all lanes get total
#pragma unroll
  for (int o = 32; o; o >>= 1) v += __shfl_xor(v, o, 64);
  return v;
}

__device__ __forceinline__ ushort f2bf(float f) {
  union { float f; unsigned u; } x;
  x.f = f;
  unsigned r = x.u + 0x7fffu + ((x.u >> 16) & 1u);  // RNE
  return (ushort)(r >> 16);
}
__device__ __forceinline__ float bf2f(ushort u) {
  union { unsigned u; float f; } x;
  x.u = ((unsigned)u) << 16;
  return x.f;
}

// ========== k1: LN (wave/row) || M-GEMM || bias folds || prior gather ======
// blocks [0,1024): LN rows bid*4+w
// blocks [1024,1088): Mt = Wk@Wq^T 64x64 tile
// blocks [1088,1216): vq/vk rows (+c0 on first)
// blocks [1216,1224): prior superdiag gather
__global__ __launch_bounds__(256) void k1(
    const float* __restrict__ ctx, const float* __restrict__ gamma,
    const float* __restrict__ beta, const float* __restrict__ Wq,
    const float* __restrict__ bq, const float* __restrict__ Wk,
    const float* __restrict__ bk, const float* __restrict__ prior,
    unsigned* __restrict__ Xb, ushort* __restrict__ Mt) {
  __shared__ __align__(16) char smem[16384];
  const int bid = blockIdx.x, tid = threadIdx.x;
  const int w = tid >> 6, l = tid & 63;

  if (bid < 1024) {  // ---- LayerNorm, wave-per-row, no barriers ----
    const int row = bid * 4 + w;
    const float4* src = reinterpret_cast<const float4*>(ctx + (size_t)row * D);
    const float4 a0 = src[l * 2], a1 = src[l * 2 + 1];
    float sum = a0.x + a0.y + a0.z + a0.w + a1.x + a1.y + a1.z + a1.w;
    sum = wredx(sum);
    const float mu = sum * (1.0f / (float)D);
    float d[8] = {a0.x - mu, a0.y - mu, a0.z - mu, a0.w - mu,
                  a1.x - mu, a1.y - mu, a1.z - mu, a1.w - mu};
    float s2 = 0.f;
#pragma unroll
    for (int i = 0; i < 8; ++i) s2 += d[i] * d[i];
    s2 = wredx(s2);
    const float var = s2 * (1.0f / (float)(D - 1));
    const float inv = 1.0f / (sqrtf(var) + 1e-6f);
    const float4 g0 = reinterpret_cast<const float4*>(gamma)[l * 2];
    const float4 g1 = reinterpret_cast<const float4*>(gamma)[l * 2 + 1];
    const float4 b0 = reinterpret_cast<const float4*>(beta)[l * 2];
    const float4 b1 = reinterpret_cast<const float4*>(beta)[l * 2 + 1];
    const float gg[8] = {g0.x, g0.y, g0.z, g0.w, g1.x, g1.y, g1.z, g1.w};
    const float bb[8] = {b0.x, b0.y, b0.z, b0.w, b1.x, b1.y, b1.z, b1.w};
    unsigned u[4];
#pragma unroll
    for (int j = 0; j < 4; ++j) {
      const float ox = gg[2 * j] * d[2 * j] * inv + bb[2 * j];
      const float oy = gg[2 * j + 1] * d[2 * j + 1] * inv + bb[2 * j + 1];
      u[j] = (unsigned)f2bf(ox) | ((unsigned)f2bf(oy) << 16);
    }
    reinterpret_cast<uint4*>(Xb + (size_t)row * (D / 2))[l] =
        make_uint4(u[0], u[1], u[2], u[3]);
  } else if (bid < 1088) {  // ---- M-GEMM tile ----
    short* As = (short*)smem;
    short* Bs = (short*)(smem + 8192);
    const int tI = bid - 1024;
    const int bi = (tI >> 3) * 64, bj = (tI & 7) * 64;
    const int wr = (w >> 1) * 32, wc = (w & 1) * 32;
    const int lrow = l & 15, lgrp = l >> 4;
    const int srow = tid >> 2, schunk = (tid & 3) * 2;
    f32x4 acc[2][2] = {};
    for (int kk = 0; kk < D; kk += 64) {
      short8 va0, va1, vb0, vb1;
      const float* sa = Wk + (size_t)(bi + srow) * D + kk + schunk * 8;
      const float* sb = Wq + (size_t)(bj + srow) * D + kk + schunk * 8;
#pragma unroll
      for (int i = 0; i < 2; ++i) {
        const float4 a0 = reinterpret_cast<const float4*>(sa)[2 * i];
        const float4 a1 = reinterpret_cast<const float4*>(sa)[2 * i + 1];
        const float4 b0 = reinterpret_cast<const float4*>(sb)[2 * i];
        const float4 b1 = reinterpret_cast<const float4*>(sb)[2 * i + 1];
        short8* pa = i ? &va1 : &va0;
        short8* pb = i ? &vb1 : &vb0;
        (*pa)[0] = (short)f2bf(a0.x); (*pa)[1] = (short)f2bf(a0.y);
        (*pa)[2] = (short)f2bf(a0.z); (*pa)[3] = (short)f2bf(a0.w);
        (*pa)[4] = (short)f2bf(a1.x); (*pa)[5] = (short)f2bf(a1.y);
        (*pa)[6] = (short)f2bf(a1.z); (*pa)[7] = (short)f2bf(a1.w);
        (*pb)[0] = (short)f2bf(b0.x); (*pb)[1] = (short)f2bf(b0.y);
        (*pb)[2] = (short)f2bf(b0.z); (*pb)[3] = (short)f2bf(b0.w);
        (*pb)[4] = (short)f2bf(b1.x); (*pb)[5] = (short)f2bf(b1.y);
        (*pb)[6] = (short)f2bf(b1.z); (*pb)[7] = (short)f2bf(b1.w);
      }
      const int sw = srow & 7;
      *reinterpret_cast<short8*>(&As[srow * 64 + ((schunk ^ sw) << 3)]) = va0;
      *reinterpret_cast<short8*>(&As[srow * 64 + (((schunk + 1) ^ sw) << 3)]) = va1;
      *reinterpret_cast<short8*>(&Bs[srow * 64 + ((schunk ^ sw) << 3)]) = vb0;
      *reinterpret_cast<short8*>(&Bs[srow * 64 + (((schunk + 1) ^ sw) << 3)]) = vb1;
      __syncthreads();
#pragma unroll
      for (int ks = 0; ks < 2; ++ks) {
        short8 af[2], bfr[2];
#pragma unroll
        for (int mi = 0; mi < 2; ++mi) {
          const int r = wr + 16 * mi + lrow;
          af[mi] = *reinterpret_cast<const short8*>(
              &As[r * 64 + (((ks * 4 + lgrp) ^ (r & 7)) << 3)]);
        }
#pragma unroll
        for (int ni = 0; ni < 2; ++ni) {
          const int r = wc + 16 * ni + lrow;
          bfr[ni] = *reinterpret_cast<const short8*>(
              &Bs[r * 64 + (((ks * 4 + lgrp) ^ (r & 7)) << 3)]);
        }
#pragma unroll
        for (int mi = 0; mi < 2; ++mi)
#pragma unroll
          for (int ni = 0; ni < 2; ++ni)
            acc[mi][ni] = __builtin_amdgcn_mfma_f32_16x16x32_bf16(
                af[mi], bfr[ni], acc[mi][ni], 0, 0, 0);
      }
      __syncthreads();
    }
#pragma unroll
    for (int mi = 0; mi < 2; ++mi)
#pragma unroll
      for (int ni = 0; ni < 2; ++ni)
#pragma unroll
        for (int v = 0; v < 4; ++v) {
          const int r = bi + wr + 16 * mi + (l >> 4) * 4 + v;
          const int c = bj + wc + 16 * ni + (l & 15);
          Mt[(size_t)r * D + c] = f2bf(acc[mi][ni][v]);
        }
  } else if (bid < 1216) {  // ---- bias folds ----
    const int i = (bid - 1088) * 4 + w;
    float sq = 0.f, sk = 0.f;
    for (int j = l; j < D; j += 64) {
      sq += Wq[(size_t)i * D + j] * bk[j];
      sk += Wk[(size_t)i * D + j] * bq[j];
    }
    sq = wred(sq);
    sk = wred(sk);
    if (l == 0) {
      g_vq[i] = sq;
      g_vk[i] = sk;
    }
    if (bid == 1088 && tid < 64) {
      float c = 0.f;
      for (int j = l; j < D; j += 64) c += bq[j] * bk[j];
      c = wred(c);
      if (l == 0) g_c0[0] = c;
    }
  } else {  // ---- prior superdiagonal gather ----
    const int g0 = ((bid - 1216) * 256 + tid) * 2;
#pragma unroll
    for (int r = 0; r < 2; ++r) {
      const int idx = g0 + r;
      const int b = idx >> 10, s = idx & (S - 1);
      g_prsd[idx] =
          (s < S - 1) ? prior[((size_t)b * S + s) * S + s + 1] : 0.0f;
    }
  }
}

// ========== k2: banddot (+ alpha/beta for n0==0 blocks) ==========
__global__ __launch_bounds__(256) void k_banddot(const ushort* __restrict__ Xb2,
                                                 const ushort* __restrict__ Mt) {
  __shared__ __align__(16) short As[64 * 64];
  __shared__ __align__(16) short Bs[64 * 64];
  const int tid = threadIdx.x;
  const int r0 = (blockIdx.x & 63) * 64, n0 = (blockIdx.x >> 6) * 64;
  const int w = tid >> 6, l = tid & 63;
  const int wr = (w >> 1) * 32, wc = (w & 1) * 32;
  const int lrow = l & 15, lgrp = l >> 4;
  const int srow = tid >> 2, schunk = (tid & 3) * 2;
  const bool do_ab = (n0 == 0);
  f32x4 acc[2][2] = {};
  float a_p = 0.f, b_p = 0.f;
  for (int kk = 0; kk < D; kk += 64) {
    const short* sa = (const short*)Xb2 + (size_t)(r0 + srow) * D + kk + schunk * 8;
    const short* sb = (const short*)Mt + (size_t)(n0 + srow) * D + kk + schunk * 8;
    short8 va0 = reinterpret_cast<const short8*>(sa)[0];
    short8 va1 = reinterpret_cast<const short8*>(sa)[1];
    short8 vb0 = reinterpret_cast<const short8*>(sb)[0];
    short8 vb1 = reinterpret_cast<const short8*>(sb)[1];
    if (do_ab) {
      const int k0 = kk + schunk * 8;
#pragma unroll
      for (int j = 0; j < 8; ++j) {
        a_p += bf2f((ushort)va0[j]) * g_vq[k0 + j] +
               bf2f((ushort)va1[j]) * g_vq[k0 + 8 + j];
        b_p += bf2f((ushort)va0[j]) * g_vk[k0 + j] +
               bf2f((ushort)va1[j]) * g_vk[k0 + 8 + j];
      }
    }
    const int sw = srow & 7;
    *reinterpret_cast<short8*>(&As[srow * 64 + ((schunk ^ sw) << 3)]) = va0;
    *reinterpret_cast<short8*>(&As[srow * 64 + (((schunk + 1) ^ sw) << 3)]) = va1;
    *reinterpret_cast<short8*>(&Bs[srow * 64 + ((schunk ^ sw) << 3)]) = vb0;
    *reinterpret_cast<short8*>(&Bs[srow * 64 + (((schunk + 1) ^ sw) << 3)]) = vb1;
    __syncthreads();
#pragma unroll
    for (int ks = 0; ks < 2; ++ks) {
      short8 af[2], bfr[2];
#pragma unroll
      for (int mi = 0; mi < 2; ++mi) {
        const int r = wr + 16 * mi + lrow;
        af[mi] = *reinterpret_cast<const short8*>(
            &As[r * 64 + (((ks * 4 + lgrp) ^ (r & 7)) << 3)]);
      }
#pragma unroll
      for (int ni = 0; ni < 2; ++ni) {
        const int r = wc + 16 * ni + lrow;
        bfr[ni] = *reinterpret_cast<const short8*>(
            &Bs[r * 64 + (((ks * 4 + lgrp) ^ (r & 7)) << 3)]);
      }
#pragma unroll
      for (int mi = 0; mi < 2; ++mi)
#pragma unroll
        for (int ni = 0; ni < 2; ++ni)
          acc[mi][ni] = __builtin_amdgcn_mfma_f32_16x16x32_bf16(
              af[mi], bfr[ni], acc[mi][ni], 0, 0, 0);
    }
    __syncthreads();
  }
  if (do_ab) {
    a_p += __shfl_xor(a_p, 1, 64);
    a_p += __shfl_xor(a_p, 2, 64);
    b_p += __shfl_xor(b_p, 1, 64);
    b_p += __shfl_xor(b_p, 2, 64);
    if ((tid & 3) == 0) {
      g_alpha[r0 + srow] = a_p;
      g_beta[r0 + srow] = b_p;
    }
  }
  float tu[2][4] = {}, td[2][4] = {};
#pragma unroll
  for (int mi = 0; mi < 2; ++mi)
#pragma unroll
    for (int v = 0; v < 4; ++v) {
      const int grow = r0 + wr + 16 * mi + lgrp * 4 + v;
      const int sl = grow & (S - 1);
#pragma unroll
      for (int ni = 0; ni < 2; ++ni) {
        const int ncol = n0 + wc + 16 * ni + lrow;
        const float y = acc[mi][ni][v];
        if (sl < S - 1) tu[mi][v] += y * bf2f(Xb2[(size_t)(grow + 1) * D + ncol]);
        if (sl > 0) td[mi][v] += y * bf2f(Xb2[(size_t)(grow - 1) * D + ncol]);
      }
    }
#pragma unroll
  for (int m = 1; m <= 8; m <<= 1)
#pragma unroll
    for (int mi = 0; mi < 2; ++mi)
#pragma unroll
      for (int v = 0; v < 4; ++v) {
        tu[mi][v] += __shfl_xor(tu[mi][v], m, 64);
        td[mi][v] += __shfl_xor(td[mi][v], m, 64);
      }
  if (lrow == 0) {
    const int slot = (blockIdx.x >> 6) * 2 + (w & 1);
#pragma unroll
    for (int mi = 0; mi < 2; ++mi)
#pragma unroll
      for (int v = 0; v < 4; ++v) {
        const int grow = r0 + wr + 16 * mi + lgrp * 4 + v;
        g_tupart[slot][grow] = tu[mi][v];
        g_tdpart[slot][grow] = td[mi][v];
      }
  }
}

// ========== k3: partial-reduce + band softmax + scan ==========
__global__ __launch_bounds__(1024) void k_smscan(const int* __restrict__ eos) {
  const int b = blockIdx.x, s = threadIdx.x;
  const int idx = b * S + s;
  __shared__ float spp[S];
  __shared__ float wsum[16];
  float tuv = 0.f, tdv = 0.f;
#pragma unroll
  for (int p = 0; p < 16; ++p) {
    tuv += g_tupart[p][idx];
    tdv += g_tdpart[p][idx];
  }
  const float c = g_c0[0];
  const bool uv = (s + 1 < S) && (eos[b * S + s + 1] != 0);
  const bool dv = (s >= 1) && (eos[b * S + s - 1] != 0);
  const float su =
      uv ? (tuv + g_alpha[idx] + g_beta[idx + 1] + c) * (1.0f / 256.0f) : -1e9f;
  const float sd =
      dv ? (tdv + g_alpha[idx] + g_beta[idx - 1] + c) * (1.0f / 256.0f) : -1e9f;
  const float m = fmaxf(su, sd);
  const float eu = expf(su - m), ed = expf(sd - m);
  const float inv = 1.0f / (eu + ed);
  const float pn = eu * inv, pp = ed * inv;
  spp[s] = pp;
  __syncthreads();
  float v = 0.f, L = 0.f;
  if (s < S - 1) {
    v = sqrtf(pn * spp[s + 1] + 1e-9f);
    const float pr = g_prsd[idx];
    L = logf(pr + (1.0f - pr) * v + 1e-9f);
  }
  g_nup[idx] = v;
  const int lane = s & 63, wid = s >> 6;
  float incl = L;
#pragma unroll
  for (int o = 1; o <= 32; o <<= 1) {
    const float t = __shfl_up(incl, o, 64);
    if (lane >= o) incl += t;
  }
  if (lane == 63) wsum[wid] = incl;
  __syncthreads();
  if (s < 16) {
    float x = wsum[s];
#pragma unroll
    for (int o = 1; o <= 8; o <<= 1) {
      const float t = __shfl_up(x, o, 16);
      if ((s & 15) >= o) x += t;
    }
    wsum[s] = x;
  }
  __syncthreads();
  g_C[idx] = incl - L + (wid ? wsum[wid - 1] : 0.0f);
}

// ========== k4: final outputs ==========
__global__ __launch_bounds__(256) void k_final(const float* __restrict__ prior,
                                               float* __restrict__ out0,
                                               float* __restrict__ out1) {
  const int b = blockIdx.y, i = blockIdx.x, t = threadIdx.x;
  const size_t rowoff = ((size_t)b * S + i) * S;
  const float4 pr4 = reinterpret_cast<const float4*>(prior + rowoff)[t];
  const float4 cj4 = reinterpret_cast<const float4*>(g_C + b * S)[t];
  const float ci = g_C[b * S + i];
  const float SQ = sqrtf(1e-9f);
  const float prr[4] = {pr4.x, pr4.y, pr4.z, pr4.w};
  const float cjj[4] = {cj4.x, cj4.y, cj4.z, cj4.w};
  float o0[4], o1[4];
#pragma unroll
  for (int q = 0; q < 4; ++q) {
    const int j = t * 4 + q;
    const float p = prr[q];
    float v;
    if (j == i + 1) v = g_nup[b * S + i];
    else if (j == i - 1) v = g_nup[b * S + j];
    else v = SQ;
    o1[q] = p + (1.0f - p) * v;
    if (j == i) {
      o0[q] = p + (1.0f - p) * SQ;
    } else {
      const float d = (j > i) ? (cjj[q] - ci) : (ci - cjj[q]);
      o0[q] = expf(d) + 1e-9f;
    }
  }
  reinterpret_cast<float4*>(out0 + rowoff)[t] =
      make_float4(o0[0], o0[1], o0[2], o0[3]);
  reinterpret_cast<float4*>(out1 + rowoff)[t] =
      make_float4(o1[0], o1[1], o1[2], o1[3]);
}

extern "C" void kernel_launch(void* const* d_in, const int* in_sizes, int n_in,
                              void* d_out, int out_size, void* d_ws,
                              size_t ws_size, hipStream_t stream) {
  (void)in_sizes; (void)n_in; (void)out_size; (void)d_ws; (void)ws_size;
  const float* ctx = (const float*)d_in[0];
  const float* prior = (const float*)d_in[1];
  const float* Wq = (const float*)d_in[2];
  const float* bq = (const float*)d_in[3];
  const float* Wk = (const float*)d_in[4];
  const float* bk = (const float*)d_in[5];
  const float* gamma = (const float*)d_in[6];
  const float* beta = (const float*)d_in[7];
  const int* eos = (const int*)d_in[8];

  float* ob = (float*)d_out;
  float* out0 = ob;                      // [B,S,S]
  float* out1 = ob + (size_t)B * S * S;  // [B,S,S]
  unsigned* Xb = (unsigned*)ob;          // bf16 X (floats [0,1M))
  ushort* Mt = (ushort*)(ob + 1048576);  // bf16 Mt (floats [1M,1.125M))

  k1<<<1224, 256, 0, stream>>>(ctx, gamma, beta, Wq, bq, Wk, bk, prior, Xb, Mt);
  k_banddot<<<512, 256, 0, stream>>>((const ushort*)Xb, Mt);
  k_smscan<<<B, 1024, 0, stream>>>(eos);
  k_final<<<dim3(S, B), 256, 0, stream>>>(prior, out0, out1);
}